// Round 3
// baseline (2406.504 us; speedup 1.0000x reference)
//
#include <hip/hip_runtime.h>
#include <math.h>

// Problem constants
#define Bn 256
#define Tn 100
#define In 1024
#define Hn 2048
#define On 10
#define Kc (In + Hn)   // 3072 concatenated K

typedef short s8v  __attribute__((ext_vector_type(8)));   // 8 x bf16 (as raw shorts), 4 VGPRs
typedef unsigned short us4 __attribute__((ext_vector_type(4)));
typedef float f32x4 __attribute__((ext_vector_type(4)));

__device__ __forceinline__ unsigned short f2bf(float f) {
    unsigned int u = __float_as_uint(f);
    u += 0x7fffu + ((u >> 16) & 1u);   // round-to-nearest-even
    return (unsigned short)(u >> 16);
}

// ---- setup kernels -------------------------------------------------------

// x [B][T][I] fp32 -> bf16, 4 elems/thread
__global__ void conv_x_kernel(const float4* __restrict__ src, ushort4* __restrict__ dst) {
    int i = blockIdx.x * 256 + threadIdx.x;
    float4 v = src[i];
    ushort4 o;
    o.x = f2bf(v.x); o.y = f2bf(v.y); o.z = f2bf(v.z); o.w = f2bf(v.w);
    dst[i] = o;
}

// src [K][N=2048] fp32 -> dst[n][colOff + k] bf16  (builds B^T = [Win;W]^T rows)
__global__ void transpose_bf16_kernel(const float* __restrict__ src, unsigned short* __restrict__ dst,
                                      int N, int ld, int colOff) {
    __shared__ float tile[32][33];
    int k0 = blockIdx.x * 32;
    int n0 = blockIdx.y * 32;
    int c = threadIdx.x & 31;
    int r = threadIdx.x >> 5;            // 0..7
    #pragma unroll
    for (int i = 0; i < 32; i += 8)
        tile[r + i][c] = src[(size_t)(k0 + r + i) * N + n0 + c];
    __syncthreads();
    #pragma unroll
    for (int i = 0; i < 32; i += 8)
        dst[(size_t)(n0 + r + i) * ld + colOff + k0 + c] = f2bf(tile[c][r + i]);
}

// h0 -> h_all slot 0 (bf16); lin_w [10][2048] -> padded bf16 [16][2048]; zero barrier
__global__ void small_conv_kernel(const float* __restrict__ h0, const float* __restrict__ lin_w,
                                  unsigned short* __restrict__ h_all0, unsigned short* __restrict__ lwb,
                                  unsigned int* __restrict__ bar) {
    int idx = blockIdx.x * 256 + threadIdx.x;
    if (idx == 0) *bar = 0u;             // re-zeroed every launch (ws is re-poisoned)
    if (idx < Bn * Hn) {
        h_all0[idx] = f2bf(h0[idx]);
    } else {
        int j = idx - Bn * Hn;           // < 16*2048
        int o = j >> 11;
        int k = j & 2047;
        lwb[j] = (o < On) ? f2bf(lin_w[o * Hn + k]) : (unsigned short)0;
    }
}

// ---- persistent scan -----------------------------------------------------
// 256 blocks x 512 thr (8 waves = 2/SIMD), 1 block/CU. Block tile 64m x 32n;
// n XCD-pinned via blockIdx%8 so each XCD's 256-row B^T slice (1.57 MB) stays
// L2-resident across ALL steps (no kernel-boundary invalidates). 8 waves split
// K=3072 (384 each, 12 chunks). Two-phase LDS reduce keeps LDS at 37 KB.
// Inter-step sync: device-scope release barrier on a monotonic counter.
// Readers need no acquire-invalidate: every h[t+1] line is either written
// locally (fresh dirty in own L2) or first-touch (miss -> L3, where writers'
// release wbl2 already put it). Pre-kernel poison copies are killed by the
// dispatch-time agent acquire.
__global__ __launch_bounds__(512, 2)
void scan_kernel(const unsigned short* __restrict__ xb,
                 const unsigned short* __restrict__ BTm,
                 unsigned short* __restrict__ h_all,
                 unsigned int* __restrict__ bar) {
    const int g = blockIdx.x;
    const int m0 = ((g >> 3) & 3) * 64;                 // 4 m-tiles
    const int n0 = ((g & 7) * 8 + (g >> 5)) * 32;       // 64 n-tiles, XCD-pinned
    const int w = threadIdx.x >> 6;                     // 0..7
    const int lane = threadIdx.x & 63;
    const int quad = lane >> 4;
    const int lr = lane & 15;

    __shared__ float red[4][64][36];                    // pad 36: 16B-aligned rows, 2-way banks (free)

    const unsigned short* bp0 = BTm + (size_t)(n0 + lr) * Kc;
    const unsigned short* bp1 = BTm + (size_t)(n0 + 16 + lr) * Kc;

    const int kbase = w * 384;                          // 8-wave K-split
    const size_t xrow = (size_t)Tn * In;                // x row stride (102400)

    for (int t = 0; t < Tn; ++t) {
        f32x4 acc[4][2];
        #pragma unroll
        for (int mi = 0; mi < 4; ++mi)
            #pragma unroll
            for (int ni = 0; ni < 2; ++ni)
                acc[mi][ni] = (f32x4){0.f, 0.f, 0.f, 0.f};

        const unsigned short* hprev = h_all + (size_t)t * (Bn * Hn);
        const unsigned short* xt = xb + (size_t)t * In;

        #pragma unroll
        for (int kk = 0; kk < 12; ++kk) {
            const int k0 = kbase + kk * 32;
            const int kq = k0 + quad * 8;
            const unsigned short* ab;
            size_t rstr;
            if (k0 < In) { ab = xt + kq; rstr = xrow; }           // x region (wave-uniform)
            else         { ab = hprev + (kq - In); rstr = Hn; }   // h region
            const unsigned short* arow = ab + (size_t)(m0 + lr) * rstr;
            s8v a0 = *(const s8v*)(arow);
            s8v a1 = *(const s8v*)(arow + 16 * rstr);
            s8v a2 = *(const s8v*)(arow + 32 * rstr);
            s8v a3 = *(const s8v*)(arow + 48 * rstr);
            s8v b0 = *(const s8v*)(bp0 + kq);
            s8v b1 = *(const s8v*)(bp1 + kq);
            acc[0][0] = __builtin_amdgcn_mfma_f32_16x16x32_bf16(a0, b0, acc[0][0], 0, 0, 0);
            acc[1][0] = __builtin_amdgcn_mfma_f32_16x16x32_bf16(a1, b0, acc[1][0], 0, 0, 0);
            acc[2][0] = __builtin_amdgcn_mfma_f32_16x16x32_bf16(a2, b0, acc[2][0], 0, 0, 0);
            acc[3][0] = __builtin_amdgcn_mfma_f32_16x16x32_bf16(a3, b0, acc[3][0], 0, 0, 0);
            acc[0][1] = __builtin_amdgcn_mfma_f32_16x16x32_bf16(a0, b1, acc[0][1], 0, 0, 0);
            acc[1][1] = __builtin_amdgcn_mfma_f32_16x16x32_bf16(a1, b1, acc[1][1], 0, 0, 0);
            acc[2][1] = __builtin_amdgcn_mfma_f32_16x16x32_bf16(a2, b1, acc[2][1], 0, 0, 0);
            acc[3][1] = __builtin_amdgcn_mfma_f32_16x16x32_bf16(a3, b1, acc[3][1], 0, 0, 0);
        }

        // C/D layout: row = quad*4 + reg, col = lane&15  [verified m89/m91]
        // Phase 1: waves 0..3 write their partials.
        if (w < 4) {
            #pragma unroll
            for (int mi = 0; mi < 4; ++mi)
                #pragma unroll
                for (int ni = 0; ni < 2; ++ni)
                    #pragma unroll
                    for (int rr = 0; rr < 4; ++rr)
                        red[w][mi * 16 + quad * 4 + rr][ni * 16 + lr] = acc[mi][ni][rr];
        }
        __syncthreads();
        // Phase 2: waves 4..7 accumulate into the same buffers (disjoint slots per wave).
        if (w >= 4) {
            #pragma unroll
            for (int mi = 0; mi < 4; ++mi)
                #pragma unroll
                for (int ni = 0; ni < 2; ++ni)
                    #pragma unroll
                    for (int rr = 0; rr < 4; ++rr)
                        red[w - 4][mi * 16 + quad * 4 + rr][ni * 16 + lr] += acc[mi][ni][rr];
        }
        __syncthreads();

        {   // 512 threads reduce 4 partials for 2048 outputs (4 each), tanh, store bf16
            int j = threadIdx.x << 2;
            int row = j >> 5;
            int c0 = j & 31;
            float4 s0 = *(const float4*)&red[0][row][c0];
            float4 s1 = *(const float4*)&red[1][row][c0];
            float4 s2 = *(const float4*)&red[2][row][c0];
            float4 s3 = *(const float4*)&red[3][row][c0];
            us4 o4;
            o4[0] = f2bf(tanhf(s0.x + s1.x + s2.x + s3.x));
            o4[1] = f2bf(tanhf(s0.y + s1.y + s2.y + s3.y));
            o4[2] = f2bf(tanhf(s0.z + s1.z + s2.z + s3.z));
            o4[3] = f2bf(tanhf(s0.w + s1.w + s2.w + s3.w));
            *(us4*)(h_all + (size_t)(t + 1) * (Bn * Hn) + (size_t)(m0 + row) * Hn + n0 + c0) = o4;
        }
        __syncthreads();                                 // all stores issued+drained (vmcnt0 at barrier)

        if (threadIdx.x == 0) {
            // Release: push this block's h lines to the coherence point, then count in.
            __hip_atomic_fetch_add(bar, 1u, __ATOMIC_RELEASE, __HIP_MEMORY_SCOPE_AGENT);
            const unsigned int target = 256u * (unsigned int)(t + 1);
            while (__hip_atomic_fetch_add(bar, 0u, __ATOMIC_RELAXED, __HIP_MEMORY_SCOPE_AGENT) < target)
                __builtin_amdgcn_s_sleep(2);
        }
        __syncthreads();
    }
}

// ---- output projection ---------------------------------------------------
// y[b][t][o] = h_all[t+1][b][:] . lin_w[o][:] + lin_b[o]. One 16-row wave per 16 (t,b) rows.
__global__ __launch_bounds__(256)
void gemm2_kernel(const unsigned short* __restrict__ h_all, const unsigned short* __restrict__ lwb,
                  const float* __restrict__ lb, float* __restrict__ y) {
    int gw = blockIdx.x * 4 + (threadIdx.x >> 6);       // 0..1599
    int lane = threadIdx.x & 63, quad = lane >> 4, lr = lane & 15;
    int m0 = gw * 16;
    int t = m0 >> 8;
    int b0 = m0 & 255;
    const unsigned short* ah = h_all + ((size_t)(t + 1) * Bn + b0 + lr) * Hn + quad * 8;
    const unsigned short* bh = lwb + (size_t)lr * Hn + quad * 8;
    f32x4 acc0 = {0.f, 0.f, 0.f, 0.f}, acc1 = {0.f, 0.f, 0.f, 0.f};
    #pragma unroll
    for (int k0 = 0; k0 < Hn; k0 += 64) {
        s8v a0 = *(const s8v*)(ah + k0);
        s8v b0 = *(const s8v*)(bh + k0);
        acc0 = __builtin_amdgcn_mfma_f32_16x16x32_bf16(a0, b0, acc0, 0, 0, 0);
        s8v a1 = *(const s8v*)(ah + k0 + 32);
        s8v b1 = *(const s8v*)(bh + k0 + 32);
        acc1 = __builtin_amdgcn_mfma_f32_16x16x32_bf16(a1, b1, acc1, 0, 0, 0);
    }
    acc0 = acc0 + acc1;
    if (lr < On) {
        float bias = lb[lr];
        #pragma unroll
        for (int rr = 0; rr < 4; ++rr) {
            int b = b0 + quad * 4 + rr;
            y[(size_t)b * (Tn * On) + t * On + lr] = acc0[rr] + bias;
        }
    }
}

// ---- host ----------------------------------------------------------------

extern "C" void kernel_launch(void* const* d_in, const int* in_sizes, int n_in,
                              void* d_out, int out_size, void* d_ws, size_t ws_size,
                              hipStream_t stream) {
    const float* x   = (const float*)d_in[0];
    const float* h0  = (const float*)d_in[1];
    const float* Win = (const float*)d_in[2];
    const float* W   = (const float*)d_in[3];
    const float* lw  = (const float*)d_in[4];
    const float* lb  = (const float*)d_in[5];
    float* y = (float*)d_out;

    // ws layout (bf16 elems): ~171 MB total
    unsigned short* ws    = (unsigned short*)d_ws;
    unsigned short* xb    = ws;                                  // 26,214,400 elems
    unsigned short* BTm   = xb + (size_t)Bn * Tn * In;           //  6,291,456 elems [2048][3072]
    unsigned short* h_all = BTm + (size_t)Hn * Kc;               // 52,953,088 elems [(T+1)][B][H]
    unsigned short* lwb   = h_all + (size_t)(Tn + 1) * Bn * Hn;  //     32,768 elems [16][2048]
    unsigned int*   bar   = (unsigned int*)(lwb + 32768);        // barrier counter

    conv_x_kernel<<<25600, 256, 0, stream>>>((const float4*)x, (ushort4*)xb);
    transpose_bf16_kernel<<<dim3(32, 64), 256, 0, stream>>>(Win, BTm, Hn, Kc, 0);
    transpose_bf16_kernel<<<dim3(64, 64), 256, 0, stream>>>(W, BTm, Hn, Kc, In);
    small_conv_kernel<<<2176, 256, 0, stream>>>(h0, lw, h_all, lwb, bar);

    scan_kernel<<<256, 512, 0, stream>>>(xb, BTm, h_all, bar);

    gemm2_kernel<<<400, 256, 0, stream>>>(h_all, lwb, lb, y);
}

// Round 4
// 1564.383 us; speedup vs baseline: 1.5383x; 1.5383x over previous
//
#include <hip/hip_runtime.h>
#include <math.h>

// Problem constants
#define Bn 256
#define Tn 100
#define In 1024
#define Hn 2048
#define On 10
#define Kc (In + Hn)   // 3072 concatenated K

typedef short s8v  __attribute__((ext_vector_type(8)));   // 8 x bf16 (as raw shorts), 4 VGPRs
typedef unsigned short us4 __attribute__((ext_vector_type(4)));
typedef float f32x4 __attribute__((ext_vector_type(4)));

__device__ __forceinline__ unsigned short f2bf(float f) {
    unsigned int u = __float_as_uint(f);
    u += 0x7fffu + ((u >> 16) & 1u);   // round-to-nearest-even
    return (unsigned short)(u >> 16);
}

// ---- setup kernels -------------------------------------------------------

// x [B][T][I] fp32 -> bf16, 4 elems/thread
__global__ void conv_x_kernel(const float4* __restrict__ src, ushort4* __restrict__ dst) {
    int i = blockIdx.x * 256 + threadIdx.x;
    float4 v = src[i];
    ushort4 o;
    o.x = f2bf(v.x); o.y = f2bf(v.y); o.z = f2bf(v.z); o.w = f2bf(v.w);
    dst[i] = o;
}

// src [K][N=2048] fp32 -> dst[n][colOff + k] bf16  (builds B^T = [Win;W]^T rows)
__global__ void transpose_bf16_kernel(const float* __restrict__ src, unsigned short* __restrict__ dst,
                                      int N, int ld, int colOff) {
    __shared__ float tile[32][33];
    int k0 = blockIdx.x * 32;
    int n0 = blockIdx.y * 32;
    int c = threadIdx.x & 31;
    int r = threadIdx.x >> 5;            // 0..7
    #pragma unroll
    for (int i = 0; i < 32; i += 8)
        tile[r + i][c] = src[(size_t)(k0 + r + i) * N + n0 + c];
    __syncthreads();
    #pragma unroll
    for (int i = 0; i < 32; i += 8)
        dst[(size_t)(n0 + r + i) * ld + colOff + k0 + c] = f2bf(tile[c][r + i]);
}

// h0 -> h_all slot 0 (bf16); lin_w -> padded bf16 [16][2048]; zero barrier block
__global__ void small_conv_kernel(const float* __restrict__ h0, const float* __restrict__ lin_w,
                                  unsigned short* __restrict__ h_all0, unsigned short* __restrict__ lwb,
                                  unsigned int* __restrict__ bar) {
    int idx = blockIdx.x * 256 + threadIdx.x;
    if (idx < 512) bar[idx] = 0u;        // counters + master + epoch (re-zeroed every launch)
    if (idx < Bn * Hn) {
        h_all0[idx] = f2bf(h0[idx]);
    } else {
        int j = idx - Bn * Hn;           // < 16*2048 exactly (grid sized for it)
        int o = j >> 11;
        int k = j & 2047;
        lwb[j] = (o < On) ? f2bf(lin_w[o * Hn + k]) : (unsigned short)0;
    }
}

// ---- persistent scan -----------------------------------------------------
// 256 blocks x 512 thr (8 waves = 2/SIMD), 1 block/CU. Block tile 64m x 32n;
// n XCD-pinned via blockIdx%8 so each XCD's 256-row B^T slice (1.57 MB) stays
// L2-resident across ALL steps. 8 waves split K=3072 (384 each).
//
// Sync redesign (R3 evidence: old single-counter RMW-poll barrier + per-block
// RELEASE(wbl2) cost ~17us/step -> MfmaUtil 5.8%):
//  * h writes: agent-scope RELAXED atomic stores (sc1 write-through) -> data at
//    coherence point once vmcnt drains; NO wbl2, NO release. Readers can't
//    hold stale copies (h[t+1] addresses are first-touch each step).
//  * barrier: 8 XCD-group counters (128B apart, 32 relaxed-RMW arrivals each)
//    -> master (8 arrivals) -> epoch flag; all poll epoch with relaxed atomic
//    LOADS (no ownership ping-pong) + s_sleep.
__global__ __launch_bounds__(512, 2)
void scan_kernel(const unsigned short* __restrict__ xb,
                 const unsigned short* __restrict__ BTm,
                 unsigned short* __restrict__ h_all,
                 unsigned int* __restrict__ bar) {
    const int g = blockIdx.x;
    const int m0 = ((g >> 3) & 3) * 64;                 // 4 m-tiles
    const int n0 = ((g & 7) * 8 + (g >> 5)) * 32;       // 64 n-tiles, XCD-pinned
    const int w = threadIdx.x >> 6;                     // 0..7
    const int lane = threadIdx.x & 63;
    const int quad = lane >> 4;
    const int lr = lane & 15;

    __shared__ float red[4][64][36];                    // pad 36: 16B-aligned rows, 2-way banks (free)

    const unsigned short* bp0 = BTm + (size_t)(n0 + lr) * Kc;
    const unsigned short* bp1 = BTm + (size_t)(n0 + 16 + lr) * Kc;

    const int kbase = w * 384;                          // 8-wave K-split
    const size_t xrow = (size_t)Tn * In;                // x row stride (102400)

    unsigned int* grp_cnt = bar + (g & 7) * 32;         // 8 counters, 128B apart
    unsigned int* mst_cnt = bar + 256;
    unsigned int* epoch   = bar + 288;

    for (int t = 0; t < Tn; ++t) {
        f32x4 acc[4][2];
        #pragma unroll
        for (int mi = 0; mi < 4; ++mi)
            #pragma unroll
            for (int ni = 0; ni < 2; ++ni)
                acc[mi][ni] = (f32x4){0.f, 0.f, 0.f, 0.f};

        const unsigned short* hprev = h_all + (size_t)t * (Bn * Hn);
        const unsigned short* xt = xb + (size_t)t * In;

        #pragma unroll
        for (int kk = 0; kk < 12; ++kk) {
            const int k0 = kbase + kk * 32;
            const int kq = k0 + quad * 8;
            const unsigned short* ab;
            size_t rstr;
            if (k0 < In) { ab = xt + kq; rstr = xrow; }           // x region (wave-uniform)
            else         { ab = hprev + (kq - In); rstr = Hn; }   // h region
            const unsigned short* arow = ab + (size_t)(m0 + lr) * rstr;
            s8v a0 = *(const s8v*)(arow);
            s8v a1 = *(const s8v*)(arow + 16 * rstr);
            s8v a2 = *(const s8v*)(arow + 32 * rstr);
            s8v a3 = *(const s8v*)(arow + 48 * rstr);
            s8v b0 = *(const s8v*)(bp0 + kq);
            s8v b1 = *(const s8v*)(bp1 + kq);
            acc[0][0] = __builtin_amdgcn_mfma_f32_16x16x32_bf16(a0, b0, acc[0][0], 0, 0, 0);
            acc[1][0] = __builtin_amdgcn_mfma_f32_16x16x32_bf16(a1, b0, acc[1][0], 0, 0, 0);
            acc[2][0] = __builtin_amdgcn_mfma_f32_16x16x32_bf16(a2, b0, acc[2][0], 0, 0, 0);
            acc[3][0] = __builtin_amdgcn_mfma_f32_16x16x32_bf16(a3, b0, acc[3][0], 0, 0, 0);
            acc[0][1] = __builtin_amdgcn_mfma_f32_16x16x32_bf16(a0, b1, acc[0][1], 0, 0, 0);
            acc[1][1] = __builtin_amdgcn_mfma_f32_16x16x32_bf16(a1, b1, acc[1][1], 0, 0, 0);
            acc[2][1] = __builtin_amdgcn_mfma_f32_16x16x32_bf16(a2, b1, acc[2][1], 0, 0, 0);
            acc[3][1] = __builtin_amdgcn_mfma_f32_16x16x32_bf16(a3, b1, acc[3][1], 0, 0, 0);
        }

        // C/D layout: row = quad*4 + reg, col = lane&15  [verified m89/m91]
        // Phase 1: waves 0..3 write their partials.
        if (w < 4) {
            #pragma unroll
            for (int mi = 0; mi < 4; ++mi)
                #pragma unroll
                for (int ni = 0; ni < 2; ++ni)
                    #pragma unroll
                    for (int rr = 0; rr < 4; ++rr)
                        red[w][mi * 16 + quad * 4 + rr][ni * 16 + lr] = acc[mi][ni][rr];
        }
        __syncthreads();
        // Phase 2: waves 4..7 accumulate (disjoint slots per wave).
        if (w >= 4) {
            #pragma unroll
            for (int mi = 0; mi < 4; ++mi)
                #pragma unroll
                for (int ni = 0; ni < 2; ++ni)
                    #pragma unroll
                    for (int rr = 0; rr < 4; ++rr)
                        red[w - 4][mi * 16 + quad * 4 + rr][ni * 16 + lr] += acc[mi][ni][rr];
        }
        __syncthreads();

        {   // 512 threads reduce 4 partials for 2048 outputs (4 each), tanh,
            // agent-scope write-through store (8 B) so h is at the coherence point.
            int j = threadIdx.x << 2;
            int row = j >> 5;
            int c0 = j & 31;
            float4 s0 = *(const float4*)&red[0][row][c0];
            float4 s1 = *(const float4*)&red[1][row][c0];
            float4 s2 = *(const float4*)&red[2][row][c0];
            float4 s3 = *(const float4*)&red[3][row][c0];
            us4 o4;
            o4[0] = f2bf(tanhf(s0.x + s1.x + s2.x + s3.x));
            o4[1] = f2bf(tanhf(s0.y + s1.y + s2.y + s3.y));
            o4[2] = f2bf(tanhf(s0.z + s1.z + s2.z + s3.z));
            o4[3] = f2bf(tanhf(s0.w + s1.w + s2.w + s3.w));
            unsigned long long* dst = (unsigned long long*)
                (h_all + (size_t)(t + 1) * (Bn * Hn) + (size_t)(m0 + row) * Hn + n0 + c0);
            __hip_atomic_store(dst, __builtin_bit_cast(unsigned long long, o4),
                               __ATOMIC_RELAXED, __HIP_MEMORY_SCOPE_AGENT);
        }

        if (t < Tn - 1) {
            __syncthreads();                             // drains vmcnt(0): stores are at L3
            if (threadIdx.x == 0) {
                const unsigned int tp1 = (unsigned int)(t + 1);
                unsigned int old = __hip_atomic_fetch_add(grp_cnt, 1u, __ATOMIC_RELAXED,
                                                          __HIP_MEMORY_SCOPE_AGENT);
                if (old == 32u * tp1 - 1u) {             // last of this XCD-group
                    unsigned int mo = __hip_atomic_fetch_add(mst_cnt, 1u, __ATOMIC_RELAXED,
                                                             __HIP_MEMORY_SCOPE_AGENT);
                    if (mo == 8u * tp1 - 1u)             // last group overall
                        __hip_atomic_store(epoch, tp1, __ATOMIC_RELAXED,
                                           __HIP_MEMORY_SCOPE_AGENT);
                }
                while (__hip_atomic_load(epoch, __ATOMIC_RELAXED,
                                         __HIP_MEMORY_SCOPE_AGENT) < tp1)
                    __builtin_amdgcn_s_sleep(4);
            }
            __syncthreads();
        }
    }
}

// ---- output projection ---------------------------------------------------
// y[b][t][o] = h_all[t+1][b][:] . lin_w[o][:] + lin_b[o]. One 16-row wave per 16 (t,b) rows.
__global__ __launch_bounds__(256)
void gemm2_kernel(const unsigned short* __restrict__ h_all, const unsigned short* __restrict__ lwb,
                  const float* __restrict__ lb, float* __restrict__ y) {
    int gw = blockIdx.x * 4 + (threadIdx.x >> 6);       // 0..1599
    int lane = threadIdx.x & 63, quad = lane >> 4, lr = lane & 15;
    int m0 = gw * 16;
    int t = m0 >> 8;
    int b0 = m0 & 255;
    const unsigned short* ah = h_all + ((size_t)(t + 1) * Bn + b0 + lr) * Hn + quad * 8;
    const unsigned short* bh = lwb + (size_t)lr * Hn + quad * 8;
    f32x4 acc0 = {0.f, 0.f, 0.f, 0.f}, acc1 = {0.f, 0.f, 0.f, 0.f};
    #pragma unroll
    for (int k0 = 0; k0 < Hn; k0 += 64) {
        s8v a0 = *(const s8v*)(ah + k0);
        s8v b0 = *(const s8v*)(bh + k0);
        acc0 = __builtin_amdgcn_mfma_f32_16x16x32_bf16(a0, b0, acc0, 0, 0, 0);
        s8v a1 = *(const s8v*)(ah + k0 + 32);
        s8v b1 = *(const s8v*)(bh + k0 + 32);
        acc1 = __builtin_amdgcn_mfma_f32_16x16x32_bf16(a1, b1, acc1, 0, 0, 0);
    }
    acc0 = acc0 + acc1;
    if (lr < On) {
        float bias = lb[lr];
        #pragma unroll
        for (int rr = 0; rr < 4; ++rr) {
            int b = b0 + quad * 4 + rr;
            y[(size_t)b * (Tn * On) + t * On + lr] = acc0[rr] + bias;
        }
    }
}

// ---- host ----------------------------------------------------------------

extern "C" void kernel_launch(void* const* d_in, const int* in_sizes, int n_in,
                              void* d_out, int out_size, void* d_ws, size_t ws_size,
                              hipStream_t stream) {
    const float* x   = (const float*)d_in[0];
    const float* h0  = (const float*)d_in[1];
    const float* Win = (const float*)d_in[2];
    const float* W   = (const float*)d_in[3];
    const float* lw  = (const float*)d_in[4];
    const float* lb  = (const float*)d_in[5];
    float* y = (float*)d_out;

    // ws layout (bf16 elems): ~171 MB total
    unsigned short* ws    = (unsigned short*)d_ws;
    unsigned short* xb    = ws;                                  // 26,214,400 elems
    unsigned short* BTm   = xb + (size_t)Bn * Tn * In;           //  6,291,456 elems [2048][3072]
    unsigned short* h_all = BTm + (size_t)Hn * Kc;               // 52,953,088 elems [(T+1)][B][H]
    unsigned short* lwb   = h_all + (size_t)(Tn + 1) * Bn * Hn;  //     32,768 elems [16][2048]
    unsigned int*   bar   = (unsigned int*)(lwb + 32768);        // 512 uints barrier block

    conv_x_kernel<<<25600, 256, 0, stream>>>((const float4*)x, (ushort4*)xb);
    transpose_bf16_kernel<<<dim3(32, 64), 256, 0, stream>>>(Win, BTm, Hn, Kc, 0);
    transpose_bf16_kernel<<<dim3(64, 64), 256, 0, stream>>>(W, BTm, Hn, Kc, In);
    small_conv_kernel<<<2176, 256, 0, stream>>>(h0, lw, h_all, lwb, bar);

    scan_kernel<<<256, 512, 0, stream>>>(xb, BTm, h_all, bar);

    gemm2_kernel<<<400, 256, 0, stream>>>(h_all, lwb, lb, y);
}

// Round 5
// 1529.620 us; speedup vs baseline: 1.5733x; 1.0227x over previous
//
#include <hip/hip_runtime.h>
#include <math.h>

// Problem constants
#define Bn 256
#define Tn 100
#define In 1024
#define Hn 2048
#define On 10
#define Kc (In + Hn)   // 3072 concatenated K

typedef short s8v  __attribute__((ext_vector_type(8)));   // 8 x bf16 (as raw shorts), 4 VGPRs
typedef unsigned short us4 __attribute__((ext_vector_type(4)));
typedef float f32x4 __attribute__((ext_vector_type(4)));

__device__ __forceinline__ unsigned short f2bf(float f) {
    unsigned int u = __float_as_uint(f);
    u += 0x7fffu + ((u >> 16) & 1u);   // round-to-nearest-even
    return (unsigned short)(u >> 16);
}

// ---- setup kernels -------------------------------------------------------

// x [B][T][I] fp32 -> bf16, 4 elems/thread
__global__ void conv_x_kernel(const float4* __restrict__ src, ushort4* __restrict__ dst) {
    int i = blockIdx.x * 256 + threadIdx.x;
    float4 v = src[i];
    ushort4 o;
    o.x = f2bf(v.x); o.y = f2bf(v.y); o.z = f2bf(v.z); o.w = f2bf(v.w);
    dst[i] = o;
}

// src [K][N=2048] fp32 -> dst[n][colOff + k] bf16  (builds B^T = [Win;W]^T rows)
__global__ void transpose_bf16_kernel(const float* __restrict__ src, unsigned short* __restrict__ dst,
                                      int N, int ld, int colOff) {
    __shared__ float tile[32][33];
    int k0 = blockIdx.x * 32;
    int n0 = blockIdx.y * 32;
    int c = threadIdx.x & 31;
    int r = threadIdx.x >> 5;            // 0..7
    #pragma unroll
    for (int i = 0; i < 32; i += 8)
        tile[r + i][c] = src[(size_t)(k0 + r + i) * N + n0 + c];
    __syncthreads();
    #pragma unroll
    for (int i = 0; i < 32; i += 8)
        dst[(size_t)(n0 + r + i) * ld + colOff + k0 + c] = f2bf(tile[c][r + i]);
}

// h0 -> h_all slot 0 (bf16); lin_w -> padded bf16 [16][2048]; zero barrier block
__global__ void small_conv_kernel(const float* __restrict__ h0, const float* __restrict__ lin_w,
                                  unsigned short* __restrict__ h_all0, unsigned short* __restrict__ lwb,
                                  unsigned int* __restrict__ bar) {
    int idx = blockIdx.x * 256 + threadIdx.x;
    if (idx < 512) bar[idx] = 0u;        // counters + master + epoch (re-zeroed every launch)
    if (idx < Bn * Hn) {
        h_all0[idx] = f2bf(h0[idx]);
    } else {
        int j = idx - Bn * Hn;           // < 16*2048 exactly (grid sized for it)
        int o = j >> 11;
        int k = j & 2047;
        lwb[j] = (o < On) ? f2bf(lin_w[o * Hn + k]) : (unsigned short)0;
    }
}

// ---- persistent scan -----------------------------------------------------
// 256 blocks x 512 thr (8 waves = 2/SIMD), 1 block/CU. Block tile 64m x 32n;
// n XCD-pinned via blockIdx%8 (B^T slice L2-resident). R5 changes:
//  * B-fragments PRELOADED INTO REGISTERS (24 x s8v = 96 VGPR/thread) — B
//    never re-loads after t=0 (was 1/3 of all loads, every step).
//  * per-wave K re-split: 4 x-chunks ([w*128,+128)) + 8 h-chunks
//    ([1024+w*256,+256)). x-chunks don't depend on the barrier.
//  * cross-barrier software pipeline: next step's x-part (loads+MFMA) runs
//    BEFORE the barrier arrival, filling the drain+arrival+poll window.
// Sync (proven R4): relaxed agent-scope write-through h stores; hierarchical
// barrier (8 group counters 128B apart -> master -> epoch; relaxed loads poll).
__global__ __launch_bounds__(512, 2)
void scan_kernel(const unsigned short* __restrict__ xb,
                 const unsigned short* __restrict__ BTm,
                 unsigned short* __restrict__ h_all,
                 unsigned int* __restrict__ bar) {
    const int g = blockIdx.x;
    const int m0 = ((g >> 3) & 3) * 64;                 // 4 m-tiles
    const int n0 = ((g & 7) * 8 + (g >> 5)) * 32;       // 64 n-tiles, XCD-pinned
    const int w = threadIdx.x >> 6;                     // 0..7
    const int lane = threadIdx.x & 63;
    const int quad = lane >> 4;
    const int lr = lane & 15;

    __shared__ float red[4][64][36];                    // pad 36: 2-way banks (free)

    const unsigned short* bp0 = BTm + (size_t)(n0 + lr) * Kc;
    const unsigned short* bp1 = BTm + (size_t)(n0 + 16 + lr) * Kc;

    const size_t xrow = (size_t)Tn * In;                // x row stride (102400)

    unsigned int* grp_cnt = bar + (g & 7) * 32;         // 8 counters, 128B apart
    unsigned int* mst_cnt = bar + 256;
    unsigned int* epoch   = bar + 288;

    // ---- one-time B-fragment preload (lives in registers all 100 steps) ----
    s8v bx[4][2];                                       // x-region B frags
    s8v bh[8][2];                                       // h-region B frags
    #pragma unroll
    for (int c = 0; c < 4; ++c) {
        const int kq = w * 128 + c * 32 + quad * 8;
        bx[c][0] = *(const s8v*)(bp0 + kq);
        bx[c][1] = *(const s8v*)(bp1 + kq);
    }
    #pragma unroll
    for (int c = 0; c < 8; ++c) {
        const int kq = In + w * 256 + c * 32 + quad * 8;
        bh[c][0] = *(const s8v*)(bp0 + kq);
        bh[c][1] = *(const s8v*)(bp1 + kq);
    }

    f32x4 acc[4][2];
    #pragma unroll
    for (int mi = 0; mi < 4; ++mi)
        #pragma unroll
        for (int ni = 0; ni < 2; ++ni)
            acc[mi][ni] = (f32x4){0.f, 0.f, 0.f, 0.f};

    // ---- x-part for t=0 ----
    {
        const unsigned short* xt = xb + 0 * In;
        #pragma unroll
        for (int c = 0; c < 4; ++c) {
            const int kq = w * 128 + c * 32 + quad * 8;
            const unsigned short* arow = xt + kq + (size_t)(m0 + lr) * xrow;
            s8v a0 = *(const s8v*)(arow);
            s8v a1 = *(const s8v*)(arow + 16 * xrow);
            s8v a2 = *(const s8v*)(arow + 32 * xrow);
            s8v a3 = *(const s8v*)(arow + 48 * xrow);
            acc[0][0] = __builtin_amdgcn_mfma_f32_16x16x32_bf16(a0, bx[c][0], acc[0][0], 0, 0, 0);
            acc[1][0] = __builtin_amdgcn_mfma_f32_16x16x32_bf16(a1, bx[c][0], acc[1][0], 0, 0, 0);
            acc[2][0] = __builtin_amdgcn_mfma_f32_16x16x32_bf16(a2, bx[c][0], acc[2][0], 0, 0, 0);
            acc[3][0] = __builtin_amdgcn_mfma_f32_16x16x32_bf16(a3, bx[c][0], acc[3][0], 0, 0, 0);
            acc[0][1] = __builtin_amdgcn_mfma_f32_16x16x32_bf16(a0, bx[c][1], acc[0][1], 0, 0, 0);
            acc[1][1] = __builtin_amdgcn_mfma_f32_16x16x32_bf16(a1, bx[c][1], acc[1][1], 0, 0, 0);
            acc[2][1] = __builtin_amdgcn_mfma_f32_16x16x32_bf16(a2, bx[c][1], acc[2][1], 0, 0, 0);
            acc[3][1] = __builtin_amdgcn_mfma_f32_16x16x32_bf16(a3, bx[c][1], acc[3][1], 0, 0, 0);
        }
    }

    for (int t = 0; t < Tn; ++t) {
        // ---- h-part (gated on barrier of step t-1) ----
        const unsigned short* hprev = h_all + (size_t)t * (Bn * Hn);
        #pragma unroll
        for (int c = 0; c < 8; ++c) {
            const int kq = w * 256 + c * 32 + quad * 8;            // offset inside h
            const unsigned short* arow = hprev + kq + (size_t)(m0 + lr) * Hn;
            s8v a0 = *(const s8v*)(arow);
            s8v a1 = *(const s8v*)(arow + 16 * Hn);
            s8v a2 = *(const s8v*)(arow + 32 * Hn);
            s8v a3 = *(const s8v*)(arow + 48 * Hn);
            acc[0][0] = __builtin_amdgcn_mfma_f32_16x16x32_bf16(a0, bh[c][0], acc[0][0], 0, 0, 0);
            acc[1][0] = __builtin_amdgcn_mfma_f32_16x16x32_bf16(a1, bh[c][0], acc[1][0], 0, 0, 0);
            acc[2][0] = __builtin_amdgcn_mfma_f32_16x16x32_bf16(a2, bh[c][0], acc[2][0], 0, 0, 0);
            acc[3][0] = __builtin_amdgcn_mfma_f32_16x16x32_bf16(a3, bh[c][0], acc[3][0], 0, 0, 0);
            acc[0][1] = __builtin_amdgcn_mfma_f32_16x16x32_bf16(a0, bh[c][1], acc[0][1], 0, 0, 0);
            acc[1][1] = __builtin_amdgcn_mfma_f32_16x16x32_bf16(a1, bh[c][1], acc[1][1], 0, 0, 0);
            acc[2][1] = __builtin_amdgcn_mfma_f32_16x16x32_bf16(a2, bh[c][1], acc[2][1], 0, 0, 0);
            acc[3][1] = __builtin_amdgcn_mfma_f32_16x16x32_bf16(a3, bh[c][1], acc[3][1], 0, 0, 0);
        }

        // ---- LDS reduce: C/D layout row=quad*4+reg, col=lane&15 [m89/m91] ----
        if (w < 4) {
            #pragma unroll
            for (int mi = 0; mi < 4; ++mi)
                #pragma unroll
                for (int ni = 0; ni < 2; ++ni)
                    #pragma unroll
                    for (int rr = 0; rr < 4; ++rr)
                        red[w][mi * 16 + quad * 4 + rr][ni * 16 + lr] = acc[mi][ni][rr];
        }
        __syncthreads();
        if (w >= 4) {
            #pragma unroll
            for (int mi = 0; mi < 4; ++mi)
                #pragma unroll
                for (int ni = 0; ni < 2; ++ni)
                    #pragma unroll
                    for (int rr = 0; rr < 4; ++rr)
                        red[w - 4][mi * 16 + quad * 4 + rr][ni * 16 + lr] += acc[mi][ni][rr];
        }
        __syncthreads();

        {   // final reduce + tanh + agent-scope write-through store (8 B)
            int j = threadIdx.x << 2;
            int row = j >> 5;
            int c0 = j & 31;
            float4 s0 = *(const float4*)&red[0][row][c0];
            float4 s1 = *(const float4*)&red[1][row][c0];
            float4 s2 = *(const float4*)&red[2][row][c0];
            float4 s3 = *(const float4*)&red[3][row][c0];
            us4 o4;
            o4[0] = f2bf(tanhf(s0.x + s1.x + s2.x + s3.x));
            o4[1] = f2bf(tanhf(s0.y + s1.y + s2.y + s3.y));
            o4[2] = f2bf(tanhf(s0.z + s1.z + s2.z + s3.z));
            o4[3] = f2bf(tanhf(s0.w + s1.w + s2.w + s3.w));
            unsigned long long* dst = (unsigned long long*)
                (h_all + (size_t)(t + 1) * (Bn * Hn) + (size_t)(m0 + row) * Hn + n0 + c0);
            __hip_atomic_store(dst, __builtin_bit_cast(unsigned long long, o4),
                               __ATOMIC_RELAXED, __HIP_MEMORY_SCOPE_AGENT);
        }

        if (t < Tn - 1) {
            // ---- cross-barrier pipeline: next step's x-part BEFORE arrival ----
            #pragma unroll
            for (int mi = 0; mi < 4; ++mi)
                #pragma unroll
                for (int ni = 0; ni < 2; ++ni)
                    acc[mi][ni] = (f32x4){0.f, 0.f, 0.f, 0.f};
            const unsigned short* xt = xb + (size_t)(t + 1) * In;
            #pragma unroll
            for (int c = 0; c < 4; ++c) {
                const int kq = w * 128 + c * 32 + quad * 8;
                const unsigned short* arow = xt + kq + (size_t)(m0 + lr) * xrow;
                s8v a0 = *(const s8v*)(arow);
                s8v a1 = *(const s8v*)(arow + 16 * xrow);
                s8v a2 = *(const s8v*)(arow + 32 * xrow);
                s8v a3 = *(const s8v*)(arow + 48 * xrow);
                acc[0][0] = __builtin_amdgcn_mfma_f32_16x16x32_bf16(a0, bx[c][0], acc[0][0], 0, 0, 0);
                acc[1][0] = __builtin_amdgcn_mfma_f32_16x16x32_bf16(a1, bx[c][0], acc[1][0], 0, 0, 0);
                acc[2][0] = __builtin_amdgcn_mfma_f32_16x16x32_bf16(a2, bx[c][0], acc[2][0], 0, 0, 0);
                acc[3][0] = __builtin_amdgcn_mfma_f32_16x16x32_bf16(a3, bx[c][0], acc[3][0], 0, 0, 0);
                acc[0][1] = __builtin_amdgcn_mfma_f32_16x16x32_bf16(a0, bx[c][1], acc[0][1], 0, 0, 0);
                acc[1][1] = __builtin_amdgcn_mfma_f32_16x16x32_bf16(a1, bx[c][1], acc[1][1], 0, 0, 0);
                acc[2][1] = __builtin_amdgcn_mfma_f32_16x16x32_bf16(a2, bx[c][1], acc[2][1], 0, 0, 0);
                acc[3][1] = __builtin_amdgcn_mfma_f32_16x16x32_bf16(a3, bx[c][1], acc[3][1], 0, 0, 0);
            }

            __syncthreads();                             // per-wave vmcnt(0): h stores drained
            if (threadIdx.x == 0) {
                const unsigned int tp1 = (unsigned int)(t + 1);
                unsigned int old = __hip_atomic_fetch_add(grp_cnt, 1u, __ATOMIC_RELAXED,
                                                          __HIP_MEMORY_SCOPE_AGENT);
                if (old == 32u * tp1 - 1u) {
                    unsigned int mo = __hip_atomic_fetch_add(mst_cnt, 1u, __ATOMIC_RELAXED,
                                                             __HIP_MEMORY_SCOPE_AGENT);
                    if (mo == 8u * tp1 - 1u)
                        __hip_atomic_store(epoch, tp1, __ATOMIC_RELAXED,
                                           __HIP_MEMORY_SCOPE_AGENT);
                }
                while (__hip_atomic_load(epoch, __ATOMIC_RELAXED,
                                         __HIP_MEMORY_SCOPE_AGENT) < tp1)
                    __builtin_amdgcn_s_sleep(2);
            }
            __syncthreads();
        }
    }
}

// ---- output projection ---------------------------------------------------
// y[b][t][o] = h_all[t+1][b][:] . lin_w[o][:] + lin_b[o]. One 16-row wave per 16 (t,b) rows.
__global__ __launch_bounds__(256)
void gemm2_kernel(const unsigned short* __restrict__ h_all, const unsigned short* __restrict__ lwb,
                  const float* __restrict__ lb, float* __restrict__ y) {
    int gw = blockIdx.x * 4 + (threadIdx.x >> 6);       // 0..1599
    int lane = threadIdx.x & 63, quad = lane >> 4, lr = lane & 15;
    int m0 = gw * 16;
    int t = m0 >> 8;
    int b0 = m0 & 255;
    const unsigned short* ah = h_all + ((size_t)(t + 1) * Bn + b0 + lr) * Hn + quad * 8;
    const unsigned short* bh = lwb + (size_t)lr * Hn + quad * 8;
    f32x4 acc0 = {0.f, 0.f, 0.f, 0.f}, acc1 = {0.f, 0.f, 0.f, 0.f};
    #pragma unroll
    for (int k0 = 0; k0 < Hn; k0 += 64) {
        s8v a0 = *(const s8v*)(ah + k0);
        s8v b0 = *(const s8v*)(bh + k0);
        acc0 = __builtin_amdgcn_mfma_f32_16x16x32_bf16(a0, b0, acc0, 0, 0, 0);
        s8v a1 = *(const s8v*)(ah + k0 + 32);
        s8v b1 = *(const s8v*)(bh + k0 + 32);
        acc1 = __builtin_amdgcn_mfma_f32_16x16x32_bf16(a1, b1, acc1, 0, 0, 0);
    }
    acc0 = acc0 + acc1;
    if (lr < On) {
        float bias = lb[lr];
        #pragma unroll
        for (int rr = 0; rr < 4; ++rr) {
            int b = b0 + quad * 4 + rr;
            y[(size_t)b * (Tn * On) + t * On + lr] = acc0[rr] + bias;
        }
    }
}

// ---- host ----------------------------------------------------------------

extern "C" void kernel_launch(void* const* d_in, const int* in_sizes, int n_in,
                              void* d_out, int out_size, void* d_ws, size_t ws_size,
                              hipStream_t stream) {
    const float* x   = (const float*)d_in[0];
    const float* h0  = (const float*)d_in[1];
    const float* Win = (const float*)d_in[2];
    const float* W   = (const float*)d_in[3];
    const float* lw  = (const float*)d_in[4];
    const float* lb  = (const float*)d_in[5];
    float* y = (float*)d_out;

    // ws layout (bf16 elems): ~171 MB total
    unsigned short* ws    = (unsigned short*)d_ws;
    unsigned short* xb    = ws;                                  // 26,214,400 elems
    unsigned short* BTm   = xb + (size_t)Bn * Tn * In;           //  6,291,456 elems [2048][3072]
    unsigned short* h_all = BTm + (size_t)Hn * Kc;               // 52,953,088 elems [(T+1)][B][H]
    unsigned short* lwb   = h_all + (size_t)(Tn + 1) * Bn * Hn;  //     32,768 elems [16][2048]
    unsigned int*   bar   = (unsigned int*)(lwb + 32768);        // 512 uints barrier block

    conv_x_kernel<<<25600, 256, 0, stream>>>((const float4*)x, (ushort4*)xb);
    transpose_bf16_kernel<<<dim3(32, 64), 256, 0, stream>>>(Win, BTm, Hn, Kc, 0);
    transpose_bf16_kernel<<<dim3(64, 64), 256, 0, stream>>>(W, BTm, Hn, Kc, In);
    small_conv_kernel<<<2176, 256, 0, stream>>>(h0, lw, h_all, lwb, bar);

    scan_kernel<<<256, 512, 0, stream>>>(xb, BTm, h_all, bar);

    gemm2_kernel<<<400, 256, 0, stream>>>(h_all, lwb, lb, y);
}